// Round 3
// baseline (73.888 us; speedup 1.0000x reference)
//
#include <hip/hip_runtime.h>

// NNLoss: bidirectional Chamfer NN-L1. B=16, N=M=2048, D=2, scalar f32 out.
//
// R13 == R12 resubmitted verbatim (R12 bench died infra-side: "container
// failed twice", kernel never ran; no code-attributable failure mode).
//
// R12: recovery-scatter diet. R11 post-mortem: -0.9us of predicted -1.35;
// the shortfall is recovery's per-lane scattered ds_read_b128 (random quads
// in a 512B window -> ~4-way bank conflict, ~19cyc each). R11 did 6 reads
// per query (24/thread, 384 wave-issues/block ~= 3us/CU hidden cost).
// This round:
//  - scan tracks the winning QUAD, not just octet: qs = (m23 < m01), one
//    extra cmp+cndmask per q per octet (+~0.6us VALU/SIMD). Tie -> quad 0
//    = earlier index, so exact first-index argmin semantics preserved.
//  - recovery loads only X,Y of the winning quad (2 scattered b128, not 6)
//    and recomputes t^2 = fma(x,x,y*y) -- bit-identical to zs4 staging
//    (same IEEE ops), so equality match against best[] is exact.
//  - first-match now over 4 in-quad candidates (descending overwrite =>
//    earliest index), cross-segment u64 merge unchanged.
// Recovery scattered issues: 384 -> 128 per block (~ -2us/CU).
// Predicted: dur 72.7 -> ~71.0-71.5us, absmax 0.0. If neutral: recovery
// was latency-hidden -> next lever is phase-overlap (split-db + global
// u64 atomicMin merge) or MFMA distance-matrix rewrite.

typedef float v2f __attribute__((ext_vector_type(2)));
typedef float v4f __attribute__((ext_vector_type(4)));

constexpr int B      = 16;
constexpr int NPTS   = 2048;
constexpr int BLK    = 1024;
constexpr int G      = 256;          // queries per block
constexpr int S      = 16;           // db segments (one per wave)
constexpr int QPT    = 4;            // queries per thread
constexpr int SEGLEN = NPTS / S;     // 128 points per segment
constexpr int QUADS  = SEGLEN / 4;   // 32 point-quads per segment
constexpr int OCTS   = SEGLEN / 8;   // 16 point-octets per segment
constexpr int NBLK   = 2 * B * (NPTS / G);  // 256 blocks

__global__ __launch_bounds__(BLK) void nn_main(
    const float* __restrict__ preds, const float* __restrict__ targs,
    const float* __restrict__ subcoef, float* __restrict__ out)
{
    __shared__ v4f xs4[NPTS / 4];                  // 8 KB quad-packed x
    __shared__ v4f ys4[NPTS / 4];                  // 8 KB quad-packed y
    __shared__ v4f zs4[NPTS / 4];                  // 8 KB quad-packed t^2
    __shared__ unsigned long long cand[S * G];     // 32 KB candidates
    __shared__ float ssum[BLK / 64];

    const int blk  = blockIdx.x;
    const int dir  = blk >> 7;          // 0: preds->targs (subcoef), 1: reverse
    const int b    = (blk >> 3) & 15;
    const int tile = blk & 7;

    const float2* qb = reinterpret_cast<const float2*>(dir == 0 ? preds : targs)
                       + b * NPTS + tile * G;
    const float2* db = reinterpret_cast<const float2*>(dir == 0 ? targs : preds)
                       + b * NPTS;

    // Stage db as quad-packed SoA. Threads <512 build xs4; >=512 build ys4
    // AND zs4 (t^2, fma-rounded exactly as recovery recomputes it).
    const float4* db4 = reinterpret_cast<const float4*>(db);
    {
        const int j = threadIdx.x & 511;
        const float4 a = db4[2 * j];
        const float4 c = db4[2 * j + 1];
        if (threadIdx.x < 512) {
            xs4[j] = {a.x, a.z, c.x, c.z};
        } else {
            ys4[j] = {a.y, a.w, c.y, c.w};
            zs4[j] = {fmaf(a.x, a.x, a.y * a.y), fmaf(a.z, a.z, a.w * a.w),
                      fmaf(c.x, c.x, c.y * c.y), fmaf(c.z, c.z, c.w * c.w)};
        }
    }

    const int qslot = threadIdx.x & 63;   // query slot within wave
    const int seg   = threadIdx.x >> 6;   // one 128-point segment per wave

    // 4 register-resident queries, coefficients splatted for packed fma.
    v2f   m2x[QPT], m2y[QPT];
    float best[QPT];
    int   bj[QPT];                        // best octet (0..15)
    int   bs[QPT];                        // best quad within octet (0/1)
    #pragma unroll
    for (int q = 0; q < QPT; ++q) {
        const float2 qp = qb[qslot + q * 64];
        const float ax = -2.0f * qp.x, ay = -2.0f * qp.y;
        m2x[q] = {ax, ax};
        m2y[q] = {ay, ay};
        best[q] = 3.402823466e+38f;
        bj[q] = 0;
        bs[q] = 0;
    }
    __syncthreads();

    // Scan segment, 8 points per super-iter. f(t) = t^2 - 2 q.t (monotone in
    // d^2 per query; bit-identical across segments -> exact cross-seg merge).
    const v4f* xsp = xs4 + seg * QUADS;
    const v4f* ysp = ys4 + seg * QUADS;
    const v4f* zsp = zs4 + seg * QUADS;
    #pragma unroll 2
    for (int i = 0; i < OCTS; ++i) {
        const v4f X0 = xsp[2 * i],     Y0 = ysp[2 * i],     Z0 = zsp[2 * i];
        const v4f X1 = xsp[2 * i + 1], Y1 = ysp[2 * i + 1], Z1 = zsp[2 * i + 1];
        const v2f x0 = {X0.x, X0.y}, x1 = {X0.z, X0.w};
        const v2f x2 = {X1.x, X1.y}, x3 = {X1.z, X1.w};
        const v2f y0 = {Y0.x, Y0.y}, y1 = {Y0.z, Y0.w};
        const v2f y2 = {Y1.x, Y1.y}, y3 = {Y1.z, Y1.w};
        const v2f z0 = {Z0.x, Z0.y}, z1 = {Z0.z, Z0.w};
        const v2f z2 = {Z1.x, Z1.y}, z3 = {Z1.z, Z1.w};
        #pragma unroll
        for (int q = 0; q < QPT; ++q) {
            const v2f d0 = __builtin_elementwise_fma(
                m2x[q], x0, __builtin_elementwise_fma(m2y[q], y0, z0));
            const v2f d1 = __builtin_elementwise_fma(
                m2x[q], x1, __builtin_elementwise_fma(m2y[q], y1, z1));
            const v2f d2 = __builtin_elementwise_fma(
                m2x[q], x2, __builtin_elementwise_fma(m2y[q], y2, z2));
            const v2f d3 = __builtin_elementwise_fma(
                m2x[q], x3, __builtin_elementwise_fma(m2y[q], y3, z3));
            const float m01 = fminf(fminf(d0.x, d0.y), fminf(d1.x, d1.y));
            const float m23 = fminf(fminf(d2.x, d2.y), fminf(d3.x, d3.y));
            const float dm  = fminf(m01, m23);
            const int   qs  = (m23 < m01) ? 1 : 0;   // tie -> quad 0 (earlier)
            if (dm < best[q]) { best[q] = dm; bj[q] = i; bs[q] = qs; }  // strict <
        }
    }

    // Exact index recovery: reload only the winning QUAD's X,Y (2 scattered
    // b128 per query), recompute t^2 bit-identically to staging, and take
    // the FIRST in-quad index whose distance equals best.
    #pragma unroll
    for (int q = 0; q < QPT; ++q) {
        const int ql = 2 * bj[q] + bs[q];    // winning quad (0..31)
        const v4f X = xsp[ql];
        const v4f Y = ysp[ql];
        const v2f xa = {X.x, X.y}, xb = {X.z, X.w};
        const v2f ya = {Y.x, Y.y}, yb = {Y.z, Y.w};
        const v2f t2a = __builtin_elementwise_fma(xa, xa, ya * ya);
        const v2f t2b = __builtin_elementwise_fma(xb, xb, yb * yb);
        const v2f da = __builtin_elementwise_fma(
            m2x[q], xa, __builtin_elementwise_fma(m2y[q], ya, t2a));
        const v2f dc = __builtin_elementwise_fma(
            m2x[q], xb, __builtin_elementwise_fma(m2y[q], yb, t2b));
        int off = 3;
        if (dc.x == best[q]) off = 2;
        if (da.y == best[q]) off = 1;
        if (da.x == best[q]) off = 0;
        const int idx = seg * SEGLEN + 4 * ql + off;
        unsigned int fb = __float_as_uint(best[q]);
        fb ^= 0x80000000u | (unsigned int)((int)fb >> 31);  // total-order map
        cand[seg * G + qslot + q * 64] =
            ((unsigned long long)fb << 32) | (unsigned int)idx;
    }
    __syncthreads();

    // First G threads: u64-min over 16 segment candidates = exact argmin.
    float val = 0.0f;
    if (threadIdx.x < G) {
        unsigned long long bp = cand[threadIdx.x];
        #pragma unroll
        for (int s = 1; s < S; ++s) {
            const unsigned long long v = cand[s * G + threadIdx.x];
            bp = v < bp ? v : bp;
        }
        const int idx = (int)(unsigned int)bp;
        const float2 qp = qb[threadIdx.x];
        const float2 tp = db[idx];            // scattered 8B, cache-hot
        float sx = 1.0f, sy = 1.0f;
        if (dir == 0) { sx = subcoef[0]; sy = subcoef[1]; }
        val = fabsf(qp.x - tp.x) * sx + fabsf(qp.y - tp.y) * sy;
    }

    // Block reduction, one atomic per block onto poisoned d_out (harmless).
    #pragma unroll
    for (int off = 32; off > 0; off >>= 1)
        val += __shfl_down(val, off, 64);
    if ((threadIdx.x & 63) == 0) ssum[threadIdx.x >> 6] = val;
    __syncthreads();
    if (threadIdx.x == 0) {
        float s = ssum[0];
        #pragma unroll
        for (int w = 1; w < BLK / 64; ++w) s += ssum[w];
        atomicAdd(out, s);   // device-scope: coherent across XCDs
    }
}

extern "C" void kernel_launch(void* const* d_in, const int* in_sizes, int n_in,
                              void* d_out, int out_size, void* d_ws, size_t ws_size,
                              hipStream_t stream) {
    const float* preds   = (const float*)d_in[0];
    const float* targs   = (const float*)d_in[1];
    const float* subcoef = (const float*)d_in[2];
    float* out = (float*)d_out;

    nn_main<<<NBLK, BLK, 0, stream>>>(preds, targs, subcoef, out);
}

// Round 4
// 73.311 us; speedup vs baseline: 1.0079x; 1.0079x over previous
//
#include <hip/hip_runtime.h>

// NNLoss: bidirectional Chamfer NN-L1. B=16, N=M=2048, D=2, scalar f32 out.
//
// R14: structural — 2 blocks/CU phase overlap. R13 post-mortem: recovery-
// scatter diet was neutral/negative (noise floor ±1us; recovery was
// latency-hidden). Modeled scan = ~5.5us VALU/SIMD + ~3.2us DS; nn_main
// measures ~22us => ~half is BUBBLES (staging latency, barrier drains,
// merge/reduce tail, launch ramp) running at 1 block/CU with nothing
// co-resident to hide them. This round:
//  - G 256->128, QPT 4->2, NBLK 256->512  => 2 blocks/CU
//  - LDS 40.1KB/block x2 = 80.2KB < 160KB; 32 waves/CU = max occupancy
//  - __launch_bounds__(1024, 8) forces <=64 VGPR so 2 blocks co-reside
//    (QPT=2 state ~55-60 regs; spill = main risk, check on regress)
//  - scan back to quad-granular (register-lean, same 26 cyc/quad/q as the
//    octet form; bj IS the quad -> R12's bs tracking gone, recovery still
//    2 scattered b128 + bit-identical t^2 recompute, exact first-index)
// Cost: DS-port issues/CU double (~3.2->6.4us, new pole) but one block's
// scan hides the other's staging/tail bubbles (~6-8us exposed today).
// Predicted: dur 73.9 -> ~69-71us, absmax 0.0. If regress: VGPR spill.
// If neutral: bubbles not the story -> attack DS/VALU stream itself.

typedef float v2f __attribute__((ext_vector_type(2)));
typedef float v4f __attribute__((ext_vector_type(4)));

constexpr int B      = 16;
constexpr int NPTS   = 2048;
constexpr int BLK    = 1024;
constexpr int G      = 128;          // queries per block
constexpr int S      = 16;           // db segments (one per wave)
constexpr int QPT    = 2;            // queries per thread
constexpr int SEGLEN = NPTS / S;     // 128 points per segment
constexpr int QUADS  = SEGLEN / 4;   // 32 point-quads per segment
constexpr int NBLK   = 2 * B * (NPTS / G);  // 512 blocks = 2 per CU

__global__ __launch_bounds__(BLK, 8) void nn_main(
    const float* __restrict__ preds, const float* __restrict__ targs,
    const float* __restrict__ subcoef, float* __restrict__ out)
{
    __shared__ v4f xs4[NPTS / 4];                  // 8 KB quad-packed x
    __shared__ v4f ys4[NPTS / 4];                  // 8 KB quad-packed y
    __shared__ v4f zs4[NPTS / 4];                  // 8 KB quad-packed t^2
    __shared__ unsigned long long cand[S * G];     // 16 KB candidates
    __shared__ float ssum[BLK / 64];

    const int blk  = blockIdx.x;
    const int dir  = blk >> 8;          // 0: preds->targs (subcoef), 1: reverse
    const int b    = (blk >> 4) & 15;
    const int tile = blk & 15;

    const float2* qb = reinterpret_cast<const float2*>(dir == 0 ? preds : targs)
                       + b * NPTS + tile * G;
    const float2* db = reinterpret_cast<const float2*>(dir == 0 ? targs : preds)
                       + b * NPTS;

    // Stage db as quad-packed SoA. Threads <512 build xs4; >=512 build ys4
    // AND zs4 (t^2, fma-rounded exactly as recovery recomputes it).
    const float4* db4 = reinterpret_cast<const float4*>(db);
    {
        const int j = threadIdx.x & 511;
        const float4 a = db4[2 * j];
        const float4 c = db4[2 * j + 1];
        if (threadIdx.x < 512) {
            xs4[j] = {a.x, a.z, c.x, c.z};
        } else {
            ys4[j] = {a.y, a.w, c.y, c.w};
            zs4[j] = {fmaf(a.x, a.x, a.y * a.y), fmaf(a.z, a.z, a.w * a.w),
                      fmaf(c.x, c.x, c.y * c.y), fmaf(c.z, c.z, c.w * c.w)};
        }
    }

    const int qslot = threadIdx.x & 63;   // query slot within wave
    const int seg   = threadIdx.x >> 6;   // one 128-point segment per wave

    // QPT register-resident queries, coefficients splatted for packed fma.
    v2f   m2x[QPT], m2y[QPT];
    float best[QPT];
    int   bj[QPT];                        // best quad (0..31)
    #pragma unroll
    for (int q = 0; q < QPT; ++q) {
        const float2 qp = qb[qslot + q * 64];
        const float ax = -2.0f * qp.x, ay = -2.0f * qp.y;
        m2x[q] = {ax, ax};
        m2y[q] = {ay, ay};
        best[q] = 3.402823466e+38f;
        bj[q] = 0;
    }
    __syncthreads();

    // Scan segment, 4 points per iter. f(t) = t^2 - 2 q.t (monotone in d^2
    // per query; bit-identical across segments -> exact cross-seg merge).
    // Strict < keeps the EARLIEST winning quad (quads ascend in index).
    const v4f* xsp = xs4 + seg * QUADS;
    const v4f* ysp = ys4 + seg * QUADS;
    const v4f* zsp = zs4 + seg * QUADS;
    #pragma unroll 2
    for (int i = 0; i < QUADS; ++i) {
        const v4f X = xsp[i], Y = ysp[i], Z = zsp[i];   // uniform b128 reads
        const v2f xa = {X.x, X.y}, xb = {X.z, X.w};
        const v2f ya = {Y.x, Y.y}, yb = {Y.z, Y.w};
        const v2f za = {Z.x, Z.y}, zb = {Z.z, Z.w};
        #pragma unroll
        for (int q = 0; q < QPT; ++q) {
            const v2f da = __builtin_elementwise_fma(
                m2x[q], xa, __builtin_elementwise_fma(m2y[q], ya, za));
            const v2f dc = __builtin_elementwise_fma(
                m2x[q], xb, __builtin_elementwise_fma(m2y[q], yb, zb));
            const float dm = fminf(fminf(da.x, da.y), fminf(dc.x, dc.y));
            if (dm < best[q]) { best[q] = dm; bj[q] = i; }  // strict <
        }
    }

    // Exact index recovery: reload only the winning quad's X,Y (2 scattered
    // b128 per query), recompute t^2 bit-identically to staging, and take
    // the FIRST in-quad index whose distance equals best.
    #pragma unroll
    for (int q = 0; q < QPT; ++q) {
        const v4f X = xsp[bj[q]];
        const v4f Y = ysp[bj[q]];
        const v2f xa = {X.x, X.y}, xb = {X.z, X.w};
        const v2f ya = {Y.x, Y.y}, yb = {Y.z, Y.w};
        const v2f t2a = __builtin_elementwise_fma(xa, xa, ya * ya);
        const v2f t2b = __builtin_elementwise_fma(xb, xb, yb * yb);
        const v2f da = __builtin_elementwise_fma(
            m2x[q], xa, __builtin_elementwise_fma(m2y[q], ya, t2a));
        const v2f dc = __builtin_elementwise_fma(
            m2x[q], xb, __builtin_elementwise_fma(m2y[q], yb, t2b));
        int off = 3;
        if (dc.x == best[q]) off = 2;
        if (da.y == best[q]) off = 1;
        if (da.x == best[q]) off = 0;
        const int idx = seg * SEGLEN + 4 * bj[q] + off;
        unsigned int fb = __float_as_uint(best[q]);
        fb ^= 0x80000000u | (unsigned int)((int)fb >> 31);  // total-order map
        cand[seg * G + qslot + q * 64] =
            ((unsigned long long)fb << 32) | (unsigned int)idx;
    }
    __syncthreads();

    // First G threads: u64-min over 16 segment candidates = exact argmin.
    float val = 0.0f;
    if (threadIdx.x < G) {
        unsigned long long bp = cand[threadIdx.x];
        #pragma unroll
        for (int s = 1; s < S; ++s) {
            const unsigned long long v = cand[s * G + threadIdx.x];
            bp = v < bp ? v : bp;
        }
        const int idx = (int)(unsigned int)bp;
        const float2 qp = qb[threadIdx.x];
        const float2 tp = db[idx];            // scattered 8B, cache-hot
        float sx = 1.0f, sy = 1.0f;
        if (dir == 0) { sx = subcoef[0]; sy = subcoef[1]; }
        val = fabsf(qp.x - tp.x) * sx + fabsf(qp.y - tp.y) * sy;
    }

    // Block reduction, one atomic per block onto poisoned d_out (harmless).
    #pragma unroll
    for (int off = 32; off > 0; off >>= 1)
        val += __shfl_down(val, off, 64);
    if ((threadIdx.x & 63) == 0) ssum[threadIdx.x >> 6] = val;
    __syncthreads();
    if (threadIdx.x == 0) {
        float s = ssum[0];
        #pragma unroll
        for (int w = 1; w < BLK / 64; ++w) s += ssum[w];
        atomicAdd(out, s);   // device-scope: coherent across XCDs
    }
}

extern "C" void kernel_launch(void* const* d_in, const int* in_sizes, int n_in,
                              void* d_out, int out_size, void* d_ws, size_t ws_size,
                              hipStream_t stream) {
    const float* preds   = (const float*)d_in[0];
    const float* targs   = (const float*)d_in[1];
    const float* subcoef = (const float*)d_in[2];
    float* out = (float*)d_out;

    nn_main<<<NBLK, BLK, 0, stream>>>(preds, targs, subcoef, out);
}